// Round 1
// baseline (1625.368 us; speedup 1.0000x reference)
//
#include <hip/hip_runtime.h>
#include <math.h>

// Deformable-DETR encoder: 2 layers of MSDA + FFN, fp32.
// B=2, S=13294 (levels 100x100, 50x50, 25x25, 13x13), D=256, NH=8, NP=4, NL=4, DFF=1024.

#define S_TOT 13294
#define BATCH 2
#define M_TOT (BATCH * S_TOT)   // 26588

// ---------------------------------------------------------------------------
// GEMM: C[M,N] = A[M,K] @ W[K,N] + bias[N]  (+ R[M,N])  (optional relu)
// 64x64 tile, BK=16, 256 threads, 4x4 microtile per thread.
// M may be ragged; N,K are multiples of 64/16 in this problem.
// ---------------------------------------------------------------------------
template<bool RELU, bool RES>
__global__ __launch_bounds__(256)
void gemm_kernel(const float* __restrict__ A, const float* __restrict__ W,
                 const float* __restrict__ bias, const float* __restrict__ R,
                 float* __restrict__ C, int M, int N, int K)
{
    __shared__ float As[16][68];   // [k][m], padded
    __shared__ float Bs[16][68];   // [k][n], padded
    const int tid = threadIdx.x;
    const int tx = tid & 15;
    const int ty = tid >> 4;
    const int bm = blockIdx.y * 64;
    const int bn = blockIdx.x * 64;
    float acc[4][4] = {};

    for (int k0 = 0; k0 < K; k0 += 16) {
        #pragma unroll
        for (int i = 0; i < 4; ++i) {
            int idx = tid + i * 256;          // 0..1023
            int m  = idx >> 4;
            int kk = idx & 15;
            int gm = bm + m;
            As[kk][m] = (gm < M) ? A[(size_t)gm * K + (k0 + kk)] : 0.0f;
        }
        #pragma unroll
        for (int i = 0; i < 4; ++i) {
            int idx = tid + i * 256;
            int kk = idx >> 6;
            int n  = idx & 63;
            Bs[kk][n] = W[(size_t)(k0 + kk) * N + (bn + n)];
        }
        __syncthreads();
        #pragma unroll
        for (int kk = 0; kk < 16; ++kk) {
            float a[4], b[4];
            #pragma unroll
            for (int i = 0; i < 4; ++i) a[i] = As[kk][ty * 4 + i];
            #pragma unroll
            for (int j = 0; j < 4; ++j) b[j] = Bs[kk][tx * 4 + j];
            #pragma unroll
            for (int i = 0; i < 4; ++i)
                #pragma unroll
                for (int j = 0; j < 4; ++j)
                    acc[i][j] = fmaf(a[i], b[j], acc[i][j]);
        }
        __syncthreads();
    }

    #pragma unroll
    for (int i = 0; i < 4; ++i) {
        int gm = bm + ty * 4 + i;
        if (gm >= M) continue;
        #pragma unroll
        for (int j = 0; j < 4; ++j) {
            int gn = bn + tx * 4 + j;
            float v = acc[i][j] + bias[gn];
            if (RES) v += R[(size_t)gm * N + gn];
            if (RELU) v = fmaxf(v, 0.0f);
            C[(size_t)gm * N + gn] = v;
        }
    }
}

// ---------------------------------------------------------------------------
// LayerNorm over last dim (256). One wave per row, 4 rows per block.
// ---------------------------------------------------------------------------
__global__ __launch_bounds__(256)
void ln_kernel(const float* __restrict__ X, const float* __restrict__ g,
               const float* __restrict__ bta, float* __restrict__ out, int M)
{
    const int row  = blockIdx.x * 4 + (threadIdx.x >> 6);
    const int lane = threadIdx.x & 63;
    if (row >= M) return;
    const float4 v = ((const float4*)(X + (size_t)row * 256))[lane];
    float s  = v.x + v.y + v.z + v.w;
    float s2 = v.x * v.x + v.y * v.y + v.z * v.z + v.w * v.w;
    #pragma unroll
    for (int o = 32; o > 0; o >>= 1) {
        s  += __shfl_down(s,  o, 64);
        s2 += __shfl_down(s2, o, 64);
    }
    s  = __shfl(s,  0, 64);
    s2 = __shfl(s2, 0, 64);
    const float mean = s * (1.0f / 256.0f);
    const float var  = s2 * (1.0f / 256.0f) - mean * mean;
    const float r    = rsqrtf(var + 1e-5f);
    const float4 gg = ((const float4*)g)[lane];
    const float4 bb = ((const float4*)bta)[lane];
    float4 o4;
    o4.x = (v.x - mean) * r * gg.x + bb.x;
    o4.y = (v.y - mean) * r * gg.y + bb.y;
    o4.z = (v.z - mean) * r * gg.z + bb.z;
    o4.w = (v.w - mean) * r * gg.w + bb.w;
    ((float4*)(out + (size_t)row * 256))[lane] = o4;
}

// ---------------------------------------------------------------------------
// MSDA sampling. One wave (64 threads) per (b,q): thread = (head h=t>>3,
// channel group c=(t&7)*4). Softmax over 16 attn logits per head (computed
// redundantly by the 8 threads of that head), then 16 bilinear samples
// (4 levels x 4 points), float4 gathers from value [B,S,NH*DH].
// Output layout [B,S, h*32+dh] == transpose(0,2,1,3).reshape of reference.
// ---------------------------------------------------------------------------
__global__ __launch_bounds__(64)
void msda_sample_kernel(const float* __restrict__ value,
                        const float* __restrict__ off,
                        const float* __restrict__ attn,
                        const float* __restrict__ vr,   // [B,4,2]
                        float* __restrict__ out)
{
    const int bq = blockIdx.x;
    const int b  = bq / S_TOT;
    const int q  = bq - b * S_TOT;
    const int t  = threadIdx.x;
    const int h  = t >> 3;
    const int c  = (t & 7) << 2;

    // locate query within its level (H==W per level here)
    int lq, rr, cc, Hq;
    if (q < 10000)      { lq = 0; Hq = 100; int rem = q;         rr = rem / 100; cc = rem - rr * 100; }
    else if (q < 12500) { lq = 1; Hq = 50;  int rem = q - 10000; rr = rem / 50;  cc = rem - rr * 50; }
    else if (q < 13125) { lq = 2; Hq = 25;  int rem = q - 12500; rr = rem / 25;  cc = rem - rr * 25; }
    else                { lq = 3; Hq = 13;  int rem = q - 13125; rr = rem / 13;  cc = rem - rr * 13; }
    const float rxb = (cc + 0.5f) / (vr[(b * 4 + lq) * 2 + 0] * (float)Hq);
    const float ryb = (rr + 0.5f) / (vr[(b * 4 + lq) * 2 + 1] * (float)Hq);

    // softmax over the 16 logits of head h
    const float* lg = attn + (size_t)bq * 128 + h * 16;
    float e[16];
    float mx = -3.4e38f;
    #pragma unroll
    for (int i = 0; i < 16; ++i) mx = fmaxf(mx, lg[i]);
    float ssum = 0.0f;
    #pragma unroll
    for (int i = 0; i < 16; ++i) { e[i] = expf(lg[i] - mx); ssum += e[i]; }
    const float inv = 1.0f / ssum;

    const float* offp = off + (size_t)bq * 256 + h * 32;  // [l][p][2]
    float a0 = 0.f, a1 = 0.f, a2 = 0.f, a3 = 0.f;

    const int starts[4] = {0, 10000, 12500, 13125};
    const int HWs[4]    = {100, 50, 25, 13};

    #pragma unroll
    for (int l = 0; l < 4; ++l) {
        const int HW = HWs[l];
        const float fHW = (float)HW;
        const float refx = rxb * vr[(b * 4 + l) * 2 + 0];
        const float refy = ryb * vr[(b * 4 + l) * 2 + 1];
        const float* vbase = value + ((size_t)(b * S_TOT + starts[l])) * 256 + h * 32 + c;
        #pragma unroll
        for (int p = 0; p < 4; ++p) {
            const float ox = offp[(l * 4 + p) * 2 + 0];
            const float oy = offp[(l * 4 + p) * 2 + 1];
            const float x = (refx + ox / fHW) * fHW - 0.5f;
            const float y = (refy + oy / fHW) * fHW - 0.5f;
            const float wgt = e[l * 4 + p] * inv;
            const float x0f = floorf(x), y0f = floorf(y);
            const int x0 = (int)x0f, y0 = (int)y0f;
            const float fx = x - x0f, fy = y - y0f;
            const float w00 = (1.f - fx) * (1.f - fy) * wgt;
            const float w01 = fx * (1.f - fy) * wgt;
            const float w10 = (1.f - fx) * fy * wgt;
            const float w11 = fx * fy * wgt;
            if (x0 >= 0 && x0 < HW && y0 >= 0 && y0 < HW) {
                const float4 v = *(const float4*)(vbase + (size_t)(y0 * HW + x0) * 256);
                a0 += w00 * v.x; a1 += w00 * v.y; a2 += w00 * v.z; a3 += w00 * v.w;
            }
            if (x0 + 1 >= 0 && x0 + 1 < HW && y0 >= 0 && y0 < HW) {
                const float4 v = *(const float4*)(vbase + (size_t)(y0 * HW + x0 + 1) * 256);
                a0 += w01 * v.x; a1 += w01 * v.y; a2 += w01 * v.z; a3 += w01 * v.w;
            }
            if (x0 >= 0 && x0 < HW && y0 + 1 >= 0 && y0 + 1 < HW) {
                const float4 v = *(const float4*)(vbase + (size_t)((y0 + 1) * HW + x0) * 256);
                a0 += w10 * v.x; a1 += w10 * v.y; a2 += w10 * v.z; a3 += w10 * v.w;
            }
            if (x0 + 1 >= 0 && x0 + 1 < HW && y0 + 1 >= 0 && y0 + 1 < HW) {
                const float4 v = *(const float4*)(vbase + (size_t)((y0 + 1) * HW + x0 + 1) * 256);
                a0 += w11 * v.x; a1 += w11 * v.y; a2 += w11 * v.z; a3 += w11 * v.w;
            }
        }
    }
    float4 o4; o4.x = a0; o4.y = a1; o4.z = a2; o4.w = a3;
    *(float4*)(out + (size_t)bq * 256 + h * 32 + c) = o4;
}

// ---------------------------------------------------------------------------
// Host-side orchestration
// ---------------------------------------------------------------------------
extern "C" void kernel_launch(void* const* d_in, const int* in_sizes, int n_in,
                              void* d_out, int out_size, void* d_ws, size_t ws_size,
                              hipStream_t stream)
{
    const float* src    = (const float*)d_in[0];
    // d_in[1] spatial_shapes (int64) — static, unused
    const float* vr     = (const float*)d_in[2];
    const float* W_off  = (const float*)d_in[3];
    const float* b_off  = (const float*)d_in[4];
    const float* W_attn = (const float*)d_in[5];
    const float* b_attn = (const float*)d_in[6];
    const float* W_val  = (const float*)d_in[7];
    const float* b_val  = (const float*)d_in[8];
    const float* W_out  = (const float*)d_in[9];
    const float* b_out  = (const float*)d_in[10];
    const float* ln1_g  = (const float*)d_in[11];
    const float* ln1_b  = (const float*)d_in[12];
    const float* W1     = (const float*)d_in[13];
    const float* b1     = (const float*)d_in[14];
    const float* W2     = (const float*)d_in[15];
    const float* b2     = (const float*)d_in[16];
    const float* ln2_g  = (const float*)d_in[17];
    const float* ln2_b  = (const float*)d_in[18];
    float* out = (float*)d_out;
    float* ws  = (float*)d_ws;

    const int M = M_TOT;
    const long long BSD = (long long)M * 256;   // 6,806,528 floats
    const long long ATT = (long long)M * 128;
    float* valb  = ws;                    // [M,256] value; later reused as pre-LN1 temp
    float* offb  = ws + BSD;              // [M,256] sampling offsets
    float* attnb = ws + 2 * BSD;          // [M,128] attn logits
    float* Yb    = ws + 2 * BSD + ATT;    // [M,256] msda out / pre-LN2 temp
    float* Hb    = ws + 3 * BSD + ATT;    // FFN hidden chunk [CH,1024]
    float* Tb    = valb;

    long long rem = (long long)(ws_size / 4) - (3 * BSD + ATT);
    long long ch = rem / 1024;
    if (ch > M) ch = M;
    if (ch < 64) ch = 64;
    const int CH = (int)ch;

    const dim3 blk(256);
    const int GY = (M + 63) / 64;

    for (int i = 0; i < 2; ++i) {
        const float* xin = (i == 0) ? src : out;

        // projections: value / sampling offsets / attn logits
        gemm_kernel<false,false><<<dim3(4, GY), blk, 0, stream>>>(
            xin, W_val + i * 65536, b_val + i * 256, nullptr, valb, M, 256, 256);
        gemm_kernel<false,false><<<dim3(4, GY), blk, 0, stream>>>(
            xin, W_off + i * 65536, b_off + i * 256, nullptr, offb, M, 256, 256);
        gemm_kernel<false,false><<<dim3(2, GY), blk, 0, stream>>>(
            xin, W_attn + i * 32768, b_attn + i * 128, nullptr, attnb, M, 128, 256);

        // deformable sampling (softmax fused)
        msda_sample_kernel<<<dim3(M), dim3(64), 0, stream>>>(valb, offb, attnb, vr, Yb);

        // output projection + residual -> Tb, then LN1 -> out
        gemm_kernel<false,true><<<dim3(4, GY), blk, 0, stream>>>(
            Yb, W_out + i * 65536, b_out + i * 256, xin, Tb, M, 256, 256);
        ln_kernel<<<dim3((M + 3) / 4), blk, 0, stream>>>(
            Tb, ln1_g + i * 256, ln1_b + i * 256, out, M);

        // FFN (chunked over rows to bound workspace): h = relu(x@W1+b1); y = h@W2+b2+x
        for (int m0 = 0; m0 < M; m0 += CH) {
            const int mc = (M - m0 < CH) ? (M - m0) : CH;
            gemm_kernel<true,false><<<dim3(16, (mc + 63) / 64), blk, 0, stream>>>(
                out + (size_t)m0 * 256, W1 + i * 262144, b1 + i * 1024, nullptr, Hb, mc, 1024, 256);
            gemm_kernel<false,true><<<dim3(4, (mc + 63) / 64), blk, 0, stream>>>(
                Hb, W2 + i * 262144, b2 + i * 256, out + (size_t)m0 * 256,
                Yb + (size_t)m0 * 256, mc, 256, 1024);
        }
        // LN2 -> out
        ln_kernel<<<dim3((M + 3) / 4), blk, 0, stream>>>(
            Yb, ln2_g + i * 256, ln2_b + i * 256, out, M);
    }
}

// Round 2
// 699.619 us; speedup vs baseline: 2.3232x; 2.3232x over previous
//
#include <hip/hip_runtime.h>
#include <math.h>

// Deformable-DETR encoder, 2 layers. bf16-MFMA GEMMs + fp32 sampling/LN.
// B=2, S=13294 (100^2,50^2,25^2,13^2), D=256, NH=8, NP=4, NL=4, DFF=1024.

#define S_TOT 13294
#define BATCH 2
#define M_TOT (BATCH * S_TOT)     // 26588
#define M_PAD 26624               // 208 * 128

typedef __attribute__((ext_vector_type(8))) short short8;
typedef __attribute__((ext_vector_type(4))) float floatx4;

#define AS1C(p) ((const __attribute__((address_space(1))) void*)(p))
#define AS3(p)  ((__attribute__((address_space(3))) void*)(p))

static __device__ __forceinline__ unsigned short f2bf(float x) {
    union { float f; unsigned u; } v; v.f = x;
    unsigned r = v.u + 0x7FFFu + ((v.u >> 16) & 1u);
    return (unsigned short)(r >> 16);
}

// ---------------------------------------------------------------------------
// bf16 MFMA GEMM: C[M,N] = A[Mpad,K](bf16) @ B(from BT[N,K] bf16) + bias
//   optional residual (fp32, guarded row<M), relu, fp32 and/or bf16 outputs.
// 128x128 tile, BK=32, 256 threads = 4 waves (2x2 of 64x64), m97 staging.
// ---------------------------------------------------------------------------
template<bool RELU, bool RES, bool F32OUT, bool BF16OUT>
__global__ __launch_bounds__(256)
void mgemm(const unsigned short* __restrict__ A,
           const unsigned short* __restrict__ BT,
           const float* __restrict__ bias,
           const float* __restrict__ R,
           float* __restrict__ Cf,
           unsigned short* __restrict__ Cb,
           int M, int N, int K)
{
    __shared__ __align__(16) unsigned short smemA[128 * 32];
    __shared__ __align__(16) unsigned short smemB[128 * 32];
    const int tid  = threadIdx.x;
    const int lane = tid & 63;
    const int w    = tid >> 6;
    const int wm   = w & 1, wn = w >> 1;
    const int lr   = lane & 15, quad = lane >> 4;
    const int bm   = blockIdx.y * 128;
    const int bn   = blockIdx.x * 128;

    floatx4 acc[4][4];
    #pragma unroll
    for (int i = 0; i < 4; ++i)
        #pragma unroll
        for (int j = 0; j < 4; ++j)
            acc[i][j] = (floatx4){0.f, 0.f, 0.f, 0.f};

    // per-lane global element offsets for staging (row = chunk*16 + lane/4,
    // kbytes = (lane%4)*16 => elements (lane&3)*8)
    const int srow = lane >> 2;
    const int selt = (lane & 3) << 3;

    for (int k0 = 0; k0 < K; k0 += 32) {
        #pragma unroll
        for (int jj = 0; jj < 2; ++jj) {
            const int j = 2 * w + jj;
            const unsigned short* ga = A  + (size_t)(bm + j * 16 + srow) * K + k0 + selt;
            const unsigned short* gb = BT + (size_t)(bn + j * 16 + srow) * K + k0 + selt;
            __builtin_amdgcn_global_load_lds(AS1C(ga), AS3(smemA + j * 512), 16, 0, 0);
            __builtin_amdgcn_global_load_lds(AS1C(gb), AS3(smemB + j * 512), 16, 0, 0);
        }
        __syncthreads();

        short8 av[4], bv[4];
        #pragma unroll
        for (int mi = 0; mi < 4; ++mi)
            av[mi] = *(const short8*)&smemA[(wm * 64 + mi * 16 + lr) * 32 + quad * 8];
        #pragma unroll
        for (int ni = 0; ni < 4; ++ni)
            bv[ni] = *(const short8*)&smemB[(wn * 64 + ni * 16 + lr) * 32 + quad * 8];
        #pragma unroll
        for (int mi = 0; mi < 4; ++mi)
            #pragma unroll
            for (int ni = 0; ni < 4; ++ni)
                acc[mi][ni] = __builtin_amdgcn_mfma_f32_16x16x32_bf16(
                    av[mi], bv[ni], acc[mi][ni], 0, 0, 0);
        __syncthreads();
    }

    #pragma unroll
    for (int mi = 0; mi < 4; ++mi) {
        #pragma unroll
        for (int ni = 0; ni < 4; ++ni) {
            #pragma unroll
            for (int r = 0; r < 4; ++r) {
                const int row = bm + wm * 64 + mi * 16 + quad * 4 + r;
                const int col = bn + wn * 64 + ni * 16 + lr;
                float v = acc[mi][ni][r] + bias[col];
                if (RES) { if (row < M) v += R[(size_t)row * N + col]; }
                if (RELU) v = fmaxf(v, 0.0f);
                if (F32OUT) Cf[(size_t)row * N + col] = v;
                if (BF16OUT) Cb[(size_t)row * N + col] = f2bf(v);
            }
        }
    }
}

// ---------------------------------------------------------------------------
// fp32 [M,256] -> bf16 [M_PAD,256] with zero padding rows
// ---------------------------------------------------------------------------
__global__ __launch_bounds__(256)
void convpad(const float* __restrict__ X, unsigned short* __restrict__ Y, int M)
{
    const int idx = blockIdx.x * 256 + threadIdx.x;   // 4 elements each
    const int row = idx >> 6;
    const int c4  = (idx & 63) << 2;
    if (row >= M_PAD) return;
    float4 v = {0.f, 0.f, 0.f, 0.f};
    if (row < M) v = ((const float4*)(X + (size_t)row * 256))[c4 >> 2];
    unsigned p0 = (unsigned)f2bf(v.x) | ((unsigned)f2bf(v.y) << 16);
    unsigned p1 = (unsigned)f2bf(v.z) | ((unsigned)f2bf(v.w) << 16);
    uint2 o; o.x = p0; o.y = p1;
    *(uint2*)(Y + (size_t)row * 256 + c4) = o;
}

// ---------------------------------------------------------------------------
// Weight transpose+convert: W[K,N] fp32 -> WT[N,K] bf16. 32x32 tiles.
// ---------------------------------------------------------------------------
__global__ __launch_bounds__(256)
void wtrans(const float* __restrict__ W, unsigned short* __restrict__ WT,
            int K, int N)
{
    __shared__ float t[32][33];
    const int n0 = blockIdx.x * 32, k0 = blockIdx.y * 32;
    const int c = threadIdx.x & 31, r0 = threadIdx.x >> 5;
    #pragma unroll
    for (int rr = r0; rr < 32; rr += 8)
        t[rr][c] = W[(size_t)(k0 + rr) * N + n0 + c];
    __syncthreads();
    #pragma unroll
    for (int rr = r0; rr < 32; rr += 8)
        WT[(size_t)(n0 + rr) * K + k0 + c] = f2bf(t[c][rr]);
}

// ---------------------------------------------------------------------------
// LayerNorm over 256. One wave per row; optional bf16 copy output.
// In-place (out == X) is safe: each row read fully before write.
// ---------------------------------------------------------------------------
__global__ __launch_bounds__(256)
void ln_kernel(const float* __restrict__ X, const float* __restrict__ g,
               const float* __restrict__ bta, float* __restrict__ out,
               unsigned short* __restrict__ outb, int M)
{
    const int row  = blockIdx.x * 4 + (threadIdx.x >> 6);
    const int lane = threadIdx.x & 63;
    if (row >= M) return;
    const float4 v = ((const float4*)(X + (size_t)row * 256))[lane];
    float s  = v.x + v.y + v.z + v.w;
    float s2 = v.x * v.x + v.y * v.y + v.z * v.z + v.w * v.w;
    #pragma unroll
    for (int o = 32; o > 0; o >>= 1) {
        s  += __shfl_down(s,  o, 64);
        s2 += __shfl_down(s2, o, 64);
    }
    s  = __shfl(s,  0, 64);
    s2 = __shfl(s2, 0, 64);
    const float mean = s * (1.0f / 256.0f);
    const float var  = s2 * (1.0f / 256.0f) - mean * mean;
    const float r    = rsqrtf(var + 1e-5f);
    const float4 gg = ((const float4*)g)[lane];
    const float4 bb = ((const float4*)bta)[lane];
    float4 o4;
    o4.x = (v.x - mean) * r * gg.x + bb.x;
    o4.y = (v.y - mean) * r * gg.y + bb.y;
    o4.z = (v.z - mean) * r * gg.z + bb.z;
    o4.w = (v.w - mean) * r * gg.w + bb.w;
    ((float4*)(out + (size_t)row * 256))[lane] = o4;
    if (outb) {
        unsigned p0 = (unsigned)f2bf(o4.x) | ((unsigned)f2bf(o4.y) << 16);
        unsigned p1 = (unsigned)f2bf(o4.z) | ((unsigned)f2bf(o4.w) << 16);
        uint2 ob; ob.x = p0; ob.y = p1;
        *(uint2*)(outb + (size_t)row * 256 + lane * 4) = ob;
    }
}

// ---------------------------------------------------------------------------
// MSDA sampling. 4 queries per 256-thread block (one wave each).
// thread = (head h = t>>3, channel group c = (t&7)*4). Writes bf16 output.
// ---------------------------------------------------------------------------
__global__ __launch_bounds__(256)
void msda_sample_kernel(const float* __restrict__ value,
                        const float* __restrict__ off,
                        const float* __restrict__ attn,
                        const float* __restrict__ vr,
                        unsigned short* __restrict__ out)
{
    const int bq = blockIdx.x * 4 + (threadIdx.x >> 6);
    const int b  = bq / S_TOT;
    const int q  = bq - b * S_TOT;
    const int t  = threadIdx.x & 63;
    const int h  = t >> 3;
    const int c  = (t & 7) << 2;

    int lq, rr, cc, Hq;
    if (q < 10000)      { lq = 0; Hq = 100; int rem = q;         rr = rem / 100; cc = rem - rr * 100; }
    else if (q < 12500) { lq = 1; Hq = 50;  int rem = q - 10000; rr = rem / 50;  cc = rem - rr * 50; }
    else if (q < 13125) { lq = 2; Hq = 25;  int rem = q - 12500; rr = rem / 25;  cc = rem - rr * 25; }
    else                { lq = 3; Hq = 13;  int rem = q - 13125; rr = rem / 13;  cc = rem - rr * 13; }
    const float rxb = (cc + 0.5f) / (vr[(b * 4 + lq) * 2 + 0] * (float)Hq);
    const float ryb = (rr + 0.5f) / (vr[(b * 4 + lq) * 2 + 1] * (float)Hq);

    const float* lg = attn + (size_t)bq * 128 + h * 16;
    float e[16];
    float mx = -3.4e38f;
    #pragma unroll
    for (int i = 0; i < 16; ++i) mx = fmaxf(mx, lg[i]);
    float ssum = 0.0f;
    #pragma unroll
    for (int i = 0; i < 16; ++i) { e[i] = expf(lg[i] - mx); ssum += e[i]; }
    const float inv = 1.0f / ssum;

    const float* offp = off + (size_t)bq * 256 + h * 32;
    float a0 = 0.f, a1 = 0.f, a2 = 0.f, a3 = 0.f;

    const int starts[4] = {0, 10000, 12500, 13125};
    const int HWs[4]    = {100, 50, 25, 13};

    #pragma unroll
    for (int l = 0; l < 4; ++l) {
        const int HW = HWs[l];
        const float fHW = (float)HW;
        const float refx = rxb * vr[(b * 4 + l) * 2 + 0];
        const float refy = ryb * vr[(b * 4 + l) * 2 + 1];
        const float* vbase = value + ((size_t)(b * S_TOT + starts[l])) * 256 + h * 32 + c;
        #pragma unroll
        for (int p = 0; p < 4; ++p) {
            const float ox = offp[(l * 4 + p) * 2 + 0];
            const float oy = offp[(l * 4 + p) * 2 + 1];
            const float x = (refx + ox / fHW) * fHW - 0.5f;
            const float y = (refy + oy / fHW) * fHW - 0.5f;
            const float wgt = e[l * 4 + p] * inv;
            const float x0f = floorf(x), y0f = floorf(y);
            const int x0 = (int)x0f, y0 = (int)y0f;
            const float fx = x - x0f, fy = y - y0f;
            const float w00 = (1.f - fx) * (1.f - fy) * wgt;
            const float w01 = fx * (1.f - fy) * wgt;
            const float w10 = (1.f - fx) * fy * wgt;
            const float w11 = fx * fy * wgt;
            if (x0 >= 0 && x0 < HW && y0 >= 0 && y0 < HW) {
                const float4 v = *(const float4*)(vbase + (size_t)(y0 * HW + x0) * 256);
                a0 += w00 * v.x; a1 += w00 * v.y; a2 += w00 * v.z; a3 += w00 * v.w;
            }
            if (x0 + 1 >= 0 && x0 + 1 < HW && y0 >= 0 && y0 < HW) {
                const float4 v = *(const float4*)(vbase + (size_t)(y0 * HW + x0 + 1) * 256);
                a0 += w01 * v.x; a1 += w01 * v.y; a2 += w01 * v.z; a3 += w01 * v.w;
            }
            if (x0 >= 0 && x0 < HW && y0 + 1 >= 0 && y0 + 1 < HW) {
                const float4 v = *(const float4*)(vbase + (size_t)((y0 + 1) * HW + x0) * 256);
                a0 += w10 * v.x; a1 += w10 * v.y; a2 += w10 * v.z; a3 += w10 * v.w;
            }
            if (x0 + 1 >= 0 && x0 + 1 < HW && y0 + 1 >= 0 && y0 + 1 < HW) {
                const float4 v = *(const float4*)(vbase + (size_t)((y0 + 1) * HW + x0 + 1) * 256);
                a0 += w11 * v.x; a1 += w11 * v.y; a2 += w11 * v.z; a3 += w11 * v.w;
            }
        }
    }
    unsigned p0 = (unsigned)f2bf(a0) | ((unsigned)f2bf(a1) << 16);
    unsigned p1 = (unsigned)f2bf(a2) | ((unsigned)f2bf(a3) << 16);
    uint2 o; o.x = p0; o.y = p1;
    *(uint2*)(out + (size_t)bq * 256 + h * 32 + c) = o;
}

// ---------------------------------------------------------------------------
// Host-side orchestration
// ---------------------------------------------------------------------------
extern "C" void kernel_launch(void* const* d_in, const int* in_sizes, int n_in,
                              void* d_out, int out_size, void* d_ws, size_t ws_size,
                              hipStream_t stream)
{
    const float* src    = (const float*)d_in[0];
    const float* vr     = (const float*)d_in[2];
    const float* W_off  = (const float*)d_in[3];
    const float* b_off  = (const float*)d_in[4];
    const float* W_attn = (const float*)d_in[5];
    const float* b_attn = (const float*)d_in[6];
    const float* W_val  = (const float*)d_in[7];
    const float* b_val  = (const float*)d_in[8];
    const float* W_out  = (const float*)d_in[9];
    const float* b_out  = (const float*)d_in[10];
    const float* ln1_g  = (const float*)d_in[11];
    const float* ln1_b  = (const float*)d_in[12];
    const float* W1     = (const float*)d_in[13];
    const float* b1     = (const float*)d_in[14];
    const float* W2     = (const float*)d_in[15];
    const float* b2     = (const float*)d_in[16];
    const float* ln2_g  = (const float*)d_in[17];
    const float* ln2_b  = (const float*)d_in[18];
    float* out = (float*)d_out;

    const int M = M_TOT;

    // --- workspace layout (bytes) ---
    // RA  [0,            27,262,976)  fp32 T1/X1/T2 (2nd half doubles as ATT)
    // RB  [27,262,976,   40,894,464)  bf16 Xbf / X1BF
    // RC  [40,894,464,   68,157,440)  fp32 VAL   \ overlay: HBF bf16 [M_PAD,1024]
    // RD  [68,157,440,   95,420,416)  fp32 OFF   /
    // RE  [95,420,416,  109,051,904)  bf16 YBF
    // WT  [109,051,904, 112,066,560)  bf16 transposed weights (both layers)
    char* wsb = (char*)d_ws;
    float*          RA  = (float*)wsb;
    unsigned short* RB  = (unsigned short*)(wsb + 27262976);
    float*          VAL = (float*)(wsb + 40894464);
    float*          OFF = (float*)(wsb + 68157440);
    unsigned short* HBF = (unsigned short*)(wsb + 40894464);
    unsigned short* YBF = (unsigned short*)(wsb + 95420416);
    unsigned short* WT  = (unsigned short*)(wsb + 109051904);
    float*          ATT = RA + 3407872;   // second half of RA
    float*          T1  = RA;             // also X1 / T2 (in-place)

    // per-layer WT offsets (elements)
    const size_t LWT = 753664;
    const size_t oVal = 0, oOff = 65536, oAtt = 131072, oOut = 163840,
                 oW1 = 229376, oW2 = 491520;

    // --- weight transposes (both layers) ---
    for (int i = 0; i < 2; ++i) {
        unsigned short* wt = WT + i * LWT;
        wtrans<<<dim3(256/32, 256/32), 256, 0, stream>>>(W_val  + i * 65536,  wt + oVal, 256, 256);
        wtrans<<<dim3(256/32, 256/32), 256, 0, stream>>>(W_off  + i * 65536,  wt + oOff, 256, 256);
        wtrans<<<dim3(128/32, 256/32), 256, 0, stream>>>(W_attn + i * 32768,  wt + oAtt, 256, 128);
        wtrans<<<dim3(256/32, 256/32), 256, 0, stream>>>(W_out  + i * 65536,  wt + oOut, 256, 256);
        wtrans<<<dim3(1024/32, 256/32), 256, 0, stream>>>(W1    + i * 262144, wt + oW1, 256, 1024);
        wtrans<<<dim3(256/32, 1024/32), 256, 0, stream>>>(W2    + i * 262144, wt + oW2, 1024, 256);
    }

    const int GM = M_PAD / 128;   // 208
    const dim3 blk(256);

    for (int i = 0; i < 2; ++i) {
        const float* xin = (i == 0) ? src : out;
        unsigned short* wt = WT + i * LWT;

        // x -> bf16 padded
        convpad<<<dim3(M_PAD / 4), blk, 0, stream>>>(xin, RB, M);

        // projections
        mgemm<false,false,true,false><<<dim3(2, GM), blk, 0, stream>>>(
            RB, wt + oVal, b_val + i * 256, nullptr, VAL, nullptr, M, 256, 256);
        mgemm<false,false,true,false><<<dim3(2, GM), blk, 0, stream>>>(
            RB, wt + oOff, b_off + i * 256, nullptr, OFF, nullptr, M, 256, 256);
        mgemm<false,false,true,false><<<dim3(1, GM), blk, 0, stream>>>(
            RB, wt + oAtt, b_attn + i * 128, nullptr, ATT, nullptr, M, 128, 256);

        // deformable sampling (softmax fused), writes bf16
        msda_sample_kernel<<<dim3(M / 4), blk, 0, stream>>>(VAL, OFF, ATT, vr, YBF);

        // out-proj + residual -> T1 (fp32), LN1 -> X1 (in-place) + X1BF (RB)
        mgemm<false,true,true,false><<<dim3(2, GM), blk, 0, stream>>>(
            YBF, wt + oOut, b_out + i * 256, xin, T1, nullptr, M, 256, 256);
        ln_kernel<<<dim3((M + 3) / 4), blk, 0, stream>>>(
            T1, ln1_g + i * 256, ln1_b + i * 256, T1, RB, M);

        // FFN1: relu, bf16 hidden (overlays VAL/OFF)
        mgemm<true,false,false,true><<<dim3(8, GM), blk, 0, stream>>>(
            RB, wt + oW1, b1 + i * 1024, nullptr, nullptr, HBF, M, 1024, 256);
        // FFN2: + residual X1 (=T1), write T2 in-place over X1
        mgemm<false,true,true,false><<<dim3(2, GM), blk, 0, stream>>>(
            HBF, wt + oW2, b2 + i * 256, T1, T1, nullptr, M, 256, 1024);

        // LN2 -> out
        ln_kernel<<<dim3((M + 3) / 4), blk, 0, stream>>>(
            T1, ln2_g + i * 256, ln2_b + i * 256, out, nullptr, M);
    }
}

// Round 4
// 550.846 us; speedup vs baseline: 2.9507x; 1.2701x over previous
//
#include <hip/hip_runtime.h>
#include <math.h>

// Deformable-DETR encoder, 2 layers. bf16-MFMA GEMMs + 2-phase MSDA sampling.
// B=2, S=13294 (100^2,50^2,25^2,13^2), D=256, NH=8, NP=4, NL=4, DFF=1024.

#define S_TOT 13294
#define BATCH 2
#define M_TOT (BATCH * S_TOT)     // 26588
#define M_PAD 26624               // 208 * 128

typedef __attribute__((ext_vector_type(8))) short short8;
typedef __attribute__((ext_vector_type(4))) float floatx4;

#define AS1C(p) ((const __attribute__((address_space(1))) void*)(p))
#define AS3(p)  ((__attribute__((address_space(3))) void*)(p))

static __device__ __forceinline__ unsigned short f2bf(float x) {
    union { float f; unsigned u; } v; v.f = x;
    unsigned r = v.u + 0x7FFFu + ((v.u >> 16) & 1u);
    return (unsigned short)(r >> 16);
}
static __device__ __forceinline__ float bflo(unsigned u) {
    union { unsigned u; float f; } v; v.u = u << 16; return v.f;
}
static __device__ __forceinline__ float bfhi(unsigned u) {
    union { unsigned u; float f; } v; v.u = u & 0xFFFF0000u; return v.f;
}

// ---------------------------------------------------------------------------
// bf16 MFMA GEMM: C[M,N] = A[Mpad,K](bf16) @ B(from BT[N,K] bf16) + bias
// split bias (concat epilogue), optional residual/relu, f32 and/or bf16 out.
// 128x128 tile, BK=32, 256 threads = 4 waves (2x2 of 64x64), m97 staging.
// ---------------------------------------------------------------------------
template<bool RELU, bool RES, bool F32OUT, bool BF16OUT>
__global__ __launch_bounds__(256)
void mgemm(const unsigned short* __restrict__ A,
           const unsigned short* __restrict__ BT,
           const float* __restrict__ bias,
           const float* __restrict__ bias2, int nsplit,
           const float* __restrict__ R,
           float* __restrict__ Cf,
           unsigned short* __restrict__ Cb,
           int M, int N, int K)
{
    __shared__ __align__(16) unsigned short smemA[128 * 32];
    __shared__ __align__(16) unsigned short smemB[128 * 32];
    const int tid  = threadIdx.x;
    const int lane = tid & 63;
    const int w    = tid >> 6;
    const int wm   = w & 1, wn = w >> 1;
    const int lr   = lane & 15, quad = lane >> 4;
    const int bm   = blockIdx.y * 128;
    const int bn   = blockIdx.x * 128;

    floatx4 acc[4][4];
    #pragma unroll
    for (int i = 0; i < 4; ++i)
        #pragma unroll
        for (int j = 0; j < 4; ++j)
            acc[i][j] = (floatx4){0.f, 0.f, 0.f, 0.f};

    const int srow = lane >> 2;
    const int selt = (lane & 3) << 3;

    for (int k0 = 0; k0 < K; k0 += 32) {
        #pragma unroll
        for (int jj = 0; jj < 2; ++jj) {
            const int j = 2 * w + jj;
            const unsigned short* ga = A  + (size_t)(bm + j * 16 + srow) * K + k0 + selt;
            const unsigned short* gb = BT + (size_t)(bn + j * 16 + srow) * K + k0 + selt;
            __builtin_amdgcn_global_load_lds(AS1C(ga), AS3(smemA + j * 512), 16, 0, 0);
            __builtin_amdgcn_global_load_lds(AS1C(gb), AS3(smemB + j * 512), 16, 0, 0);
        }
        __syncthreads();

        short8 av[4], bv[4];
        #pragma unroll
        for (int mi = 0; mi < 4; ++mi)
            av[mi] = *(const short8*)&smemA[(wm * 64 + mi * 16 + lr) * 32 + quad * 8];
        #pragma unroll
        for (int ni = 0; ni < 4; ++ni)
            bv[ni] = *(const short8*)&smemB[(wn * 64 + ni * 16 + lr) * 32 + quad * 8];
        #pragma unroll
        for (int mi = 0; mi < 4; ++mi)
            #pragma unroll
            for (int ni = 0; ni < 4; ++ni)
                acc[mi][ni] = __builtin_amdgcn_mfma_f32_16x16x32_bf16(
                    av[mi], bv[ni], acc[mi][ni], 0, 0, 0);
        __syncthreads();
    }

    #pragma unroll
    for (int mi = 0; mi < 4; ++mi) {
        #pragma unroll
        for (int ni = 0; ni < 4; ++ni) {
            #pragma unroll
            for (int r = 0; r < 4; ++r) {
                const int row = bm + wm * 64 + mi * 16 + quad * 4 + r;
                const int col = bn + wn * 64 + ni * 16 + lr;
                float bb = (col < nsplit) ? bias[col] : bias2[col - nsplit];
                float v = acc[mi][ni][r] + bb;
                if (RES) { if (row < M) v += R[(size_t)row * N + col]; }
                if (RELU) v = fmaxf(v, 0.0f);
                if (F32OUT) Cf[(size_t)row * N + col] = v;
                if (BF16OUT) Cb[(size_t)row * N + col] = f2bf(v);
            }
        }
    }
}

// ---------------------------------------------------------------------------
// fp32 [M,256] -> bf16 [M_PAD,256] with zero padding rows (layer 0 only)
// ---------------------------------------------------------------------------
__global__ __launch_bounds__(256)
void convpad(const float* __restrict__ X, unsigned short* __restrict__ Y, int M)
{
    const int idx = blockIdx.x * 256 + threadIdx.x;
    const int row = idx >> 6;
    const int c4  = (idx & 63) << 2;
    if (row >= M_PAD) return;
    float4 v = {0.f, 0.f, 0.f, 0.f};
    if (row < M) v = ((const float4*)(X + (size_t)row * 256))[c4 >> 2];
    unsigned p0 = (unsigned)f2bf(v.x) | ((unsigned)f2bf(v.y) << 16);
    unsigned p1 = (unsigned)f2bf(v.z) | ((unsigned)f2bf(v.w) << 16);
    uint2 o; o.x = p0; o.y = p1;
    *(uint2*)(Y + (size_t)row * 256 + c4) = o;
}

// ---------------------------------------------------------------------------
// Weight transpose+convert: W[K,N] fp32 -> WT[N,K] bf16. 32x32 tiles.
// ---------------------------------------------------------------------------
__global__ __launch_bounds__(256)
void wtrans(const float* __restrict__ W, unsigned short* __restrict__ WT,
            int K, int N)
{
    __shared__ float t[32][33];
    const int n0 = blockIdx.x * 32, k0 = blockIdx.y * 32;
    const int c = threadIdx.x & 31, r0 = threadIdx.x >> 5;
    #pragma unroll
    for (int rr = r0; rr < 32; rr += 8)
        t[rr][c] = W[(size_t)(k0 + rr) * N + n0 + c];
    __syncthreads();
    #pragma unroll
    for (int rr = r0; rr < 32; rr += 8)
        WT[(size_t)(n0 + rr) * K + k0 + c] = f2bf(t[c][rr]);
}

// ---------------------------------------------------------------------------
// LayerNorm over 256. One wave per row; optional bf16 copy output.
// ---------------------------------------------------------------------------
__global__ __launch_bounds__(256)
void ln_kernel(const float* __restrict__ X, const float* __restrict__ g,
               const float* __restrict__ bta, float* __restrict__ out,
               unsigned short* __restrict__ outb, int M)
{
    const int row  = blockIdx.x * 4 + (threadIdx.x >> 6);
    const int lane = threadIdx.x & 63;
    if (row >= M) return;
    const float4 v = ((const float4*)(X + (size_t)row * 256))[lane];
    float s  = v.x + v.y + v.z + v.w;
    float s2 = v.x * v.x + v.y * v.y + v.z * v.z + v.w * v.w;
    #pragma unroll
    for (int o = 32; o > 0; o >>= 1) {
        s  += __shfl_down(s,  o, 64);
        s2 += __shfl_down(s2, o, 64);
    }
    s  = __shfl(s,  0, 64);
    s2 = __shfl(s2, 0, 64);
    const float mean = s * (1.0f / 256.0f);
    const float var  = s2 * (1.0f / 256.0f) - mean * mean;
    const float r    = rsqrtf(var + 1e-5f);
    const float4 gg = ((const float4*)g)[lane];
    const float4 bb = ((const float4*)bta)[lane];
    float4 o4;
    o4.x = (v.x - mean) * r * gg.x + bb.x;
    o4.y = (v.y - mean) * r * gg.y + bb.y;
    o4.z = (v.z - mean) * r * gg.z + bb.z;
    o4.w = (v.w - mean) * r * gg.w + bb.w;
    ((float4*)(out + (size_t)row * 256))[lane] = o4;
    if (outb) {
        unsigned p0 = (unsigned)f2bf(o4.x) | ((unsigned)f2bf(o4.y) << 16);
        unsigned p1 = (unsigned)f2bf(o4.z) | ((unsigned)f2bf(o4.w) << 16);
        uint2 ob; ob.x = p0; ob.y = p1;
        *(uint2*)(outb + (size_t)row * 256 + lane * 4) = ob;
    }
}

// ---------------------------------------------------------------------------
// MSDA, 2-phase. Block = 256 threads = 8 queries.
// Phase A: lane -> (q, h, level): softmax (width-4 shuffle) + 4 samples'
//   clamped corner indices & combined weights -> LDS (XOR-swizzled 32B recs).
// Phase B: lane -> (q, h, 8-channel group): 16 samples x 4 unconditional
//   bf16 uint4 gathers, weight=0 kills invalid corners. Writes bf16.
// ---------------------------------------------------------------------------
__global__ __launch_bounds__(256)
void msda_kernel(const unsigned short* __restrict__ valb,  // [M_PAD,256] bf16
                 const float* __restrict__ oa,             // [M_PAD,384]: off 0-255, attn 256-383
                 const float* __restrict__ vr,              // [B,4,2]
                 unsigned short* __restrict__ out)          // [M_PAD,256] bf16
{
    __shared__ __align__(16) char smeta[8 * 128 * 32];   // 32 KB
    const int t = threadIdx.x;

    // ---------------- phase A ----------------
    {
        const int wv = t >> 6, lane = t & 63;
        const int lqA = wv * 2 + (lane >> 5);          // block-local query 0..7
        const int bq = blockIdx.x * 8 + lqA;
        const int h = (lane >> 2) & 7;
        const int j = lane & 3;                        // level
        if (bq < M_TOT) {
            const int b = (bq >= S_TOT) ? 1 : 0;
            const int q = bq - b * S_TOT;
            int Hq, rr, cc;
            int lq;
            if (q < 10000)      { lq = 0; Hq = 100; rr = q / 100;              cc = q - rr * 100; }
            else if (q < 12500) { lq = 1; Hq = 50;  int r2 = q - 10000; rr = r2 / 50; cc = r2 - rr * 50; }
            else if (q < 13125) { lq = 2; Hq = 25;  int r2 = q - 12500; rr = r2 / 25; cc = r2 - rr * 25; }
            else                { lq = 3; Hq = 13;  int r2 = q - 13125; rr = r2 / 13; cc = r2 - rr * 13; }
            const float rxb = (cc + 0.5f) / (vr[(b * 4 + lq) * 2 + 0] * (float)Hq);
            const float ryb = (rr + 0.5f) / (vr[(b * 4 + lq) * 2 + 1] * (float)Hq);
            const int HWt[4] = {100, 50, 25, 13};
            const int stt[4] = {0, 10000, 12500, 13125};
            const int HW = HWt[j], st = stt[j];
            const float fW = (float)HW;
            const float refx = rxb * vr[(b * 4 + j) * 2 + 0];
            const float refy = ryb * vr[(b * 4 + j) * 2 + 1];
            const float* row = oa + (size_t)bq * 384;
            const float4 lg = *(const float4*)(row + 256 + h * 16 + j * 4);
            float mx = fmaxf(fmaxf(lg.x, lg.y), fmaxf(lg.z, lg.w));
            mx = fmaxf(mx, __shfl_xor(mx, 1, 64));
            mx = fmaxf(mx, __shfl_xor(mx, 2, 64));
            const float e0 = expf(lg.x - mx), e1 = expf(lg.y - mx);
            const float e2 = expf(lg.z - mx), e3 = expf(lg.w - mx);
            float ss = e0 + e1 + e2 + e3;
            ss += __shfl_xor(ss, 1, 64);
            ss += __shfl_xor(ss, 2, 64);
            const float inv = 1.0f / ss;
            const float4 oA = *(const float4*)(row + h * 32 + j * 8);
            const float4 oB = *(const float4*)(row + h * 32 + j * 8 + 4);
            const float oxs[4] = {oA.x, oA.z, oB.x, oB.z};
            const float oys[4] = {oA.y, oA.w, oB.y, oB.w};
            const float aw[4]  = {e0 * inv, e1 * inv, e2 * inv, e3 * inv};
            char* mb = smeta + (size_t)(lqA * 128 + h * 16 + j * 4) * 32;
            const int swz = ((h * 4 + j) & 7) << 4;
            #pragma unroll
            for (int p = 0; p < 4; ++p) {
                const float x = (refx + oxs[p] / fW) * fW - 0.5f;
                const float y = (refy + oys[p] / fW) * fW - 0.5f;
                const float x0f = floorf(x), y0f = floorf(y);
                const int x0 = (int)x0f, y0 = (int)y0f;
                const float fx = x - x0f, fy = y - y0f;
                const float wb[4] = {(1.f - fx) * (1.f - fy), fx * (1.f - fy),
                                     (1.f - fx) * fy,         fx * fy};
                const int xs[2] = {x0, x0 + 1};
                const int ys2[2] = {y0, y0 + 1};
                int iv[4]; float wv4[4];
                #pragma unroll
                for (int k = 0; k < 4; ++k) {
                    const int xi = xs[k & 1], yi = ys2[k >> 1];
                    const bool vld = ((unsigned)xi < (unsigned)HW) && ((unsigned)yi < (unsigned)HW);
                    const int xc = min(max(xi, 0), HW - 1);
                    const int yc = min(max(yi, 0), HW - 1);
                    iv[k] = ((st + yc * HW + xc) << 9) + (h << 6);  // byte offset in batch slab
                    wv4[k] = vld ? wb[k] * aw[p] : 0.0f;
                }
                int4 i4; i4.x = iv[0]; i4.y = iv[1]; i4.z = iv[2]; i4.w = iv[3];
                float4 w4; w4.x = wv4[0]; w4.y = wv4[1]; w4.z = wv4[2]; w4.w = wv4[3];
                *(int4*)(mb + ((p * 32) ^ swz)) = i4;
                *(float4*)(mb + ((p * 32 + 16) ^ swz)) = w4;
            }
        }
    }
    __syncthreads();
    // ---------------- phase B ----------------
    {
        const int lq2 = t >> 5;                 // 0..7
        const int r = t & 31;
        const int h2 = r >> 2;
        const int cg = r & 3;                   // 8 channels each
        const int bq2 = blockIdx.x * 8 + lq2;
        if (bq2 < M_TOT) {
            const int b2 = (bq2 >= S_TOT) ? 1 : 0;
            const char* vb = (const char*)valb + (size_t)b2 * ((size_t)S_TOT * 512) + cg * 16;
            float acc[8] = {0.f, 0.f, 0.f, 0.f, 0.f, 0.f, 0.f, 0.f};
            const char* mb2 = smeta + (size_t)(lq2 * 128 + h2 * 16) * 32;
            #pragma unroll 4
            for (int s = 0; s < 16; ++s) {
                const int swz2 = ((h2 * 4 + (s >> 2)) & 7) << 4;
                const int4  iv = *(const int4*)(mb2 + ((s * 32) ^ swz2));
                const float4 w4 = *(const float4*)(mb2 + ((s * 32 + 16) ^ swz2));
                const uint4 u0 = *(const uint4*)(vb + iv.x);
                const uint4 u1 = *(const uint4*)(vb + iv.y);
                const uint4 u2 = *(const uint4*)(vb + iv.z);
                const uint4 u3 = *(const uint4*)(vb + iv.w);
                #define ACC8(UU, WW) \
                    acc[0] = fmaf(WW, bflo(UU.x), acc[0]); acc[1] = fmaf(WW, bfhi(UU.x), acc[1]); \
                    acc[2] = fmaf(WW, bflo(UU.y), acc[2]); acc[3] = fmaf(WW, bfhi(UU.y), acc[3]); \
                    acc[4] = fmaf(WW, bflo(UU.z), acc[4]); acc[5] = fmaf(WW, bfhi(UU.z), acc[5]); \
                    acc[6] = fmaf(WW, bflo(UU.w), acc[6]); acc[7] = fmaf(WW, bfhi(UU.w), acc[7]);
                ACC8(u0, w4.x) ACC8(u1, w4.y) ACC8(u2, w4.z) ACC8(u3, w4.w)
                #undef ACC8
            }
            uint4 o;
            o.x = (unsigned)f2bf(acc[0]) | ((unsigned)f2bf(acc[1]) << 16);
            o.y = (unsigned)f2bf(acc[2]) | ((unsigned)f2bf(acc[3]) << 16);
            o.z = (unsigned)f2bf(acc[4]) | ((unsigned)f2bf(acc[5]) << 16);
            o.w = (unsigned)f2bf(acc[6]) | ((unsigned)f2bf(acc[7]) << 16);
            *(uint4*)(out + (size_t)bq2 * 256 + h2 * 32 + cg * 8) = o;
        }
    }
}

// ---------------------------------------------------------------------------
// Host-side orchestration
// ---------------------------------------------------------------------------
extern "C" void kernel_launch(void* const* d_in, const int* in_sizes, int n_in,
                              void* d_out, int out_size, void* d_ws, size_t ws_size,
                              hipStream_t stream)
{
    const float* src    = (const float*)d_in[0];
    const float* vr     = (const float*)d_in[2];
    const float* W_off  = (const float*)d_in[3];
    const float* b_off  = (const float*)d_in[4];
    const float* W_attn = (const float*)d_in[5];
    const float* b_attn = (const float*)d_in[6];
    const float* W_val  = (const float*)d_in[7];
    const float* b_val  = (const float*)d_in[8];
    const float* W_out  = (const float*)d_in[9];
    const float* b_out  = (const float*)d_in[10];
    const float* ln1_g  = (const float*)d_in[11];
    const float* ln1_b  = (const float*)d_in[12];
    const float* W1     = (const float*)d_in[13];
    const float* b1     = (const float*)d_in[14];
    const float* W2     = (const float*)d_in[15];
    const float* b2     = (const float*)d_in[16];
    const float* ln2_g  = (const float*)d_in[17];
    const float* ln2_b  = (const float*)d_in[18];
    float* out = (float*)d_out;

    const int M = M_TOT;

    // --- workspace (bytes), total 112,066,560 ---
    // [0,          40,894,464)  OA   f32 [M_PAD,384]    \ overlay: HBF bf16 [M_PAD,1024]
    // [40,894,464, 54,525,952)  VALB bf16 [M_PAD,256]   /
    // [54,525,952, 81,788,928)  T1   f32 [M_PAD,256]
    // [81,788,928, 95,420,416)  RB   bf16 [M_PAD,256]  (x input, bf16)
    // [95,420,416,109,051,904)  YBF  bf16 [M_PAD,256]  (msda out)
    // [109,051,904,112,066,560) WT   bf16 transposed weights (both layers)
    char* wsb = (char*)d_ws;
    float*          OA   = (float*)wsb;
    unsigned short* VALB = (unsigned short*)(wsb + 40894464);
    unsigned short* HBF  = (unsigned short*)wsb;
    float*          T1   = (float*)(wsb + 54525952);
    unsigned short* RB   = (unsigned short*)(wsb + 81788928);
    unsigned short* YBF  = (unsigned short*)(wsb + 95420416);
    unsigned short* WT   = (unsigned short*)(wsb + 109051904);

    const size_t LWT = 753664;
    const size_t oOA = 0, oVal = 98304, oOut = 163840, oW1 = 229376, oW2 = 491520;

    for (int i = 0; i < 2; ++i) {
        unsigned short* wt = WT + i * LWT;
        wtrans<<<dim3(8, 8),  256, 0, stream>>>(W_off  + i * 65536,  wt + oOA,         256, 256);
        wtrans<<<dim3(4, 8),  256, 0, stream>>>(W_attn + i * 32768,  wt + oOA + 65536, 256, 128);
        wtrans<<<dim3(8, 8),  256, 0, stream>>>(W_val  + i * 65536,  wt + oVal,        256, 256);
        wtrans<<<dim3(8, 8),  256, 0, stream>>>(W_out  + i * 65536,  wt + oOut,        256, 256);
        wtrans<<<dim3(32, 8), 256, 0, stream>>>(W1     + i * 262144, wt + oW1,         256, 1024);
        wtrans<<<dim3(8, 32), 256, 0, stream>>>(W2     + i * 262144, wt + oW2,         1024, 256);
    }

    const int GM = M_PAD / 128;   // 208
    const dim3 blk(256);

    for (int i = 0; i < 2; ++i) {
        const float* xin = (i == 0) ? src : out;
        unsigned short* wt = WT + i * LWT;

        if (i == 0)
            convpad<<<dim3(M_PAD / 4), blk, 0, stream>>>(src, RB, M);

        // value projection (bf16 out) + fused off/attn projection (f32 out)
        mgemm<false,false,false,true><<<dim3(2, GM), blk, 0, stream>>>(
            RB, wt + oVal, b_val + i * 256, b_val + i * 256, 256,
            nullptr, nullptr, VALB, M, 256, 256);
        mgemm<false,false,true,false><<<dim3(3, GM), blk, 0, stream>>>(
            RB, wt + oOA, b_off + i * 256, b_attn + i * 128, 256,
            nullptr, OA, nullptr, M, 384, 256);

        // deformable sampling (2-phase), writes bf16
        msda_kernel<<<dim3((M + 7) / 8), blk, 0, stream>>>(VALB, OA, vr, YBF);

        // out-proj + residual -> T1 (f32), LN1 -> T1 + bf16 RB
        mgemm<false,true,true,false><<<dim3(2, GM), blk, 0, stream>>>(
            YBF, wt + oOut, b_out + i * 256, b_out + i * 256, 256,
            xin, T1, nullptr, M, 256, 256);
        ln_kernel<<<dim3((M + 3) / 4), blk, 0, stream>>>(
            T1, ln1_g + i * 256, ln1_b + i * 256, T1, RB, M);

        // FFN1 (relu, bf16 hidden overlays OA+VALB), FFN2 (+resid, in-place T1)
        mgemm<true,false,false,true><<<dim3(8, GM), blk, 0, stream>>>(
            RB, wt + oW1, b1 + i * 1024, b1 + i * 1024, 1024,
            nullptr, nullptr, HBF, M, 1024, 256);
        mgemm<false,true,true,false><<<dim3(2, GM), blk, 0, stream>>>(
            HBF, wt + oW2, b2 + i * 256, b2 + i * 256, 256,
            T1, T1, nullptr, M, 256, 1024);

        // LN2 -> out (+ bf16 RB for next layer when i==0)
        ln_kernel<<<dim3((M + 3) / 4), blk, 0, stream>>>(
            T1, ln2_g + i * 256, ln2_b + i * 256, out, (i == 0) ? RB : nullptr, M);
    }
}